// Round 1
// baseline (19740.355 us; speedup 1.0000x reference)
//
#include <hip/hip_runtime.h>

// Problem constants
#define Hdim 256
#define Tdim 512
#define Fdim 16

// ws layout (floats), weights repacked as [k][m][c] (c = gate 0..3 fastest):
//   wq_ih0: [16][256][4]   off 0        (16384)
//   wq_hh0: [256][256][4]  off 16384    (262144)
//   wq_ih1: [256][256][4]  off 278528   (262144)
//   wq_hh1: [256][256][4]  off 540672   (262144)
//   biasq0: [256][4]       off 802816   (1024)   = b_ih0 + b_hh0 interleaved
//   biasq1: [256][4]       off 803840   (1024)
// total 804864 floats = 3.07 MB
#define OFF_IH0 0
#define OFF_HH0 16384
#define OFF_IH1 278528
#define OFF_HH1 540672
#define OFF_B0  802816
#define OFF_B1  803840

__global__ __launch_bounds__(256) void prep_kernel(
    const float* __restrict__ w_ih0, const float* __restrict__ w_hh0,
    const float* __restrict__ b_ih0, const float* __restrict__ b_hh0,
    const float* __restrict__ w_ih1, const float* __restrict__ w_hh1,
    const float* __restrict__ b_ih1, const float* __restrict__ b_hh1,
    float* __restrict__ ws) {
  int idx = blockIdx.x * blockDim.x + threadIdx.x;  // [0, 262144)
  int c = idx & 3;
  int m = (idx >> 2) & 255;
  int k = idx >> 10;          // k in [0,256)
  int j = c * 256 + m;        // gate row in [0,1024)
  // wq[k][m][c] = w[j][k]
  if (k < 16) ws[OFF_IH0 + idx] = w_ih0[j * 16 + k];
  ws[OFF_HH0 + idx] = w_hh0[j * 256 + k];
  ws[OFF_IH1 + idx] = w_ih1[j * 256 + k];
  ws[OFF_HH1 + idx] = w_hh1[j * 256 + k];
  if (idx < 1024) {  // idx = m*4+c here
    ws[OFF_B0 + idx] = b_ih0[j] + b_hh0[j];
    ws[OFF_B1 + idx] = b_ih1[j] + b_hh1[j];
  }
}

__device__ __forceinline__ float sigf(float x) {
  return __fdividef(1.f, 1.f + __expf(-x));
}
__device__ __forceinline__ float tanhf_fast(float x) {
  float ax = fabsf(x);
  float e = __expf(-2.f * ax);            // e in (0, 1]
  float t = __fdividef(1.f - e, 1.f + e); // tanh(|x|), safe (no inf/inf)
  return copysignf(t, x);
}
__device__ __forceinline__ float4 f4fma(float4 a, float4 w, float s) {
  a.x = fmaf(w.x, s, a.x);
  a.y = fmaf(w.y, s, a.y);
  a.z = fmaf(w.z, s, a.z);
  a.w = fmaf(w.w, s, a.w);
  return a;
}

// One block = 2 batch elements, both LSTM layers fused, persistent over time.
// Thread tid owns hidden unit tid: all 4 gates (c component of float4), cell
// state in registers; only h goes through LDS.
__global__ __launch_bounds__(256) void lstm_kernel(
    const float* __restrict__ ws, const float* __restrict__ x,
    const int* __restrict__ lengths, const float* __restrict__ fc_w,
    const float* __restrict__ fc_b, float* __restrict__ out) {
  __shared__ __align__(16) float xs[2][Fdim];
  __shared__ __align__(16) float h0s[2][Hdim];
  __shared__ __align__(16) float h1s[2][Hdim];
  __shared__ float red[256];

  const int tid = threadIdx.x;
  const int b0 = blockIdx.x * 2;
  const int b1 = b0 + 1;
  const int len0 = lengths[b0];
  const int len1 = lengths[b1];
  const int tmax = max(len0, len1);

  // weight bases, already offset to this thread's hidden unit (float4 index)
  const float4* wq_ih0 = (const float4*)(ws + OFF_IH0) + tid;  // [i][m]
  const float4* wq_hh0 = (const float4*)(ws + OFF_HH0) + tid;  // [k][m]
  const float4* wq_ih1 = (const float4*)(ws + OFF_IH1) + tid;
  const float4* wq_hh1 = (const float4*)(ws + OFF_HH1) + tid;
  const float4 bz0 = ((const float4*)(ws + OFF_B0))[tid];
  const float4 bz1 = ((const float4*)(ws + OFF_B1))[tid];

  const float* xb0 = x + (size_t)b0 * Tdim * Fdim;
  const float* xb1 = x + (size_t)b1 * Tdim * Fdim;

  h0s[0][tid] = 0.f; h0s[1][tid] = 0.f;
  h1s[0][tid] = 0.f; h1s[1][tid] = 0.f;
  float c00 = 0.f, c01 = 0.f, c10 = 0.f, c11 = 0.f;  // cell states (regs)
  float hl0 = 0.f, hl1 = 0.f;                        // captured last h1
  __syncthreads();

  for (int t = 0; t < tmax; ++t) {
    // stage x[b, t, :] into LDS (2 batches x 4 float4)
    if (tid < 8) {
      int g = tid >> 2, i4 = tid & 3;
      ((float4*)xs[g])[i4] =
          ((const float4*)(g ? xb1 : xb0))[t * (Fdim / 4) + i4];
    }
    __syncthreads();

    // ---- layer 0 gates ----
    float4 a0 = bz0, a1 = bz0;
    #pragma unroll
    for (int i4 = 0; i4 < 4; ++i4) {
      float4 xv0 = ((const float4*)xs[0])[i4];
      float4 xv1 = ((const float4*)xs[1])[i4];
      float x0c[4] = {xv0.x, xv0.y, xv0.z, xv0.w};
      float x1c[4] = {xv1.x, xv1.y, xv1.z, xv1.w};
      #pragma unroll
      for (int ii = 0; ii < 4; ++ii) {
        float4 wv = wq_ih0[(i4 * 4 + ii) * 256];
        a0 = f4fma(a0, wv, x0c[ii]);
        a1 = f4fma(a1, wv, x1c[ii]);
      }
    }
    #pragma unroll 4
    for (int k4 = 0; k4 < 64; ++k4) {
      float4 ha = ((const float4*)h0s[0])[k4];
      float4 hb = ((const float4*)h0s[1])[k4];
      float hac[4] = {ha.x, ha.y, ha.z, ha.w};
      float hbc[4] = {hb.x, hb.y, hb.z, hb.w};
      #pragma unroll
      for (int kk = 0; kk < 4; ++kk) {
        float4 wv = wq_hh0[(k4 * 4 + kk) * 256];
        a0 = f4fma(a0, wv, hac[kk]);
        a1 = f4fma(a1, wv, hbc[kk]);
      }
    }
    // layer-0 state update (gate order i,f,g,o = components x,y,z,w)
    float nh00, nh01;
    {
      float ig = sigf(a0.x), fg = sigf(a0.y), gg = tanhf_fast(a0.z), og = sigf(a0.w);
      c00 = fg * c00 + ig * gg;
      nh00 = og * tanhf_fast(c00);
    }
    {
      float ig = sigf(a1.x), fg = sigf(a1.y), gg = tanhf_fast(a1.z), og = sigf(a1.w);
      c01 = fg * c01 + ig * gg;
      nh01 = og * tanhf_fast(c01);
    }
    __syncthreads();  // everyone done reading old h0s
    h0s[0][tid] = nh00;
    h0s[1][tid] = nh01;
    __syncthreads();  // new h0s visible

    // ---- layer 1 gates: xp1 (w_ih1 @ h0) + recurrence (w_hh1 @ h1) ----
    float4 g0 = bz1, g1 = bz1;
    #pragma unroll 2
    for (int k4 = 0; k4 < 64; ++k4) {
      float4 p0 = ((const float4*)h0s[0])[k4];
      float4 p1 = ((const float4*)h0s[1])[k4];
      float4 q0 = ((const float4*)h1s[0])[k4];
      float4 q1 = ((const float4*)h1s[1])[k4];
      float p0c[4] = {p0.x, p0.y, p0.z, p0.w};
      float p1c[4] = {p1.x, p1.y, p1.z, p1.w};
      float q0c[4] = {q0.x, q0.y, q0.z, q0.w};
      float q1c[4] = {q1.x, q1.y, q1.z, q1.w};
      #pragma unroll
      for (int kk = 0; kk < 4; ++kk) {
        float4 wi = wq_ih1[(k4 * 4 + kk) * 256];
        float4 wh = wq_hh1[(k4 * 4 + kk) * 256];
        g0 = f4fma(g0, wi, p0c[kk]);
        g0 = f4fma(g0, wh, q0c[kk]);
        g1 = f4fma(g1, wi, p1c[kk]);
        g1 = f4fma(g1, wh, q1c[kk]);
      }
    }
    float nh10, nh11;
    {
      float ig = sigf(g0.x), fg = sigf(g0.y), gg = tanhf_fast(g0.z), og = sigf(g0.w);
      c10 = fg * c10 + ig * gg;
      nh10 = og * tanhf_fast(c10);
    }
    {
      float ig = sigf(g1.x), fg = sigf(g1.y), gg = tanhf_fast(g1.z), og = sigf(g1.w);
      c11 = fg * c11 + ig * gg;
      nh11 = og * tanhf_fast(c11);
    }
    __syncthreads();  // everyone done reading old h1s (and h0s)
    h1s[0][tid] = nh10;
    h1s[1][tid] = nh11;
    if (t == len0 - 1) hl0 = nh10;
    if (t == len1 - 1) hl1 = nh11;
    // no barrier needed: next iteration has 2 barriers before h1s is read
  }

  // ---- FC epilogue: out[b] = relu(h_last) . fc_w + fc_b ----
  const float fw = fc_w[tid];
  __syncthreads();
  red[tid] = fmaxf(hl0, 0.f) * fw;
  __syncthreads();
  #pragma unroll
  for (int s = 128; s > 0; s >>= 1) {
    if (tid < s) red[tid] += red[tid + s];
    __syncthreads();
  }
  if (tid == 0) out[b0] = red[0] + fc_b[0];
  __syncthreads();
  red[tid] = fmaxf(hl1, 0.f) * fw;
  __syncthreads();
  #pragma unroll
  for (int s = 128; s > 0; s >>= 1) {
    if (tid < s) red[tid] += red[tid + s];
    __syncthreads();
  }
  if (tid == 0) out[b1] = red[0] + fc_b[0];
}

extern "C" void kernel_launch(void* const* d_in, const int* in_sizes, int n_in,
                              void* d_out, int out_size, void* d_ws, size_t ws_size,
                              hipStream_t stream) {
  const float* x     = (const float*)d_in[0];
  const int*   lens  = (const int*)d_in[1];
  const float* w_ih0 = (const float*)d_in[2];
  const float* w_hh0 = (const float*)d_in[3];
  const float* b_ih0 = (const float*)d_in[4];
  const float* b_hh0 = (const float*)d_in[5];
  const float* w_ih1 = (const float*)d_in[6];
  const float* w_hh1 = (const float*)d_in[7];
  const float* b_ih1 = (const float*)d_in[8];
  const float* b_hh1 = (const float*)d_in[9];
  const float* fc_w  = (const float*)d_in[10];
  const float* fc_b  = (const float*)d_in[11];
  float* out = (float*)d_out;
  float* ws  = (float*)d_ws;

  hipLaunchKernelGGL(prep_kernel, dim3(1024), dim3(256), 0, stream,
                     w_ih0, w_hh0, b_ih0, b_hh0, w_ih1, w_hh1, b_ih1, b_hh1, ws);
  hipLaunchKernelGGL(lstm_kernel, dim3(128), dim3(256), 0, stream,
                     ws, x, lens, fc_w, fc_b, out);
}